// Round 8
// baseline (177.108 us; speedup 1.0000x reference)
//
#include <hip/hip_runtime.h>
#include <math.h>

#define N_   16
#define C_   128
#define T_   150
#define V_   25
#define NH_  8
#define DK_  32
#define DV_  128
#define B_   400      // N_*V_
#define QO_  192      // 2*DK_+DV_
#define EPS_ 1e-5f

typedef __attribute__((ext_vector_type(4))) short bf16x4;
typedef __attribute__((ext_vector_type(4))) float f32x4;
typedef __attribute__((ext_vector_type(8))) short short8;

__device__ inline f32x4 mfma16(bf16x4 a, bf16x4 b, f32x4 c) {
#if __has_builtin(__builtin_amdgcn_mfma_f32_16x16x16bf16_1k)
  return __builtin_amdgcn_mfma_f32_16x16x16bf16_1k(a, b, c, 0, 0, 0);
#else
  asm volatile("v_mfma_f32_16x16x16_bf16 %0, %1, %2, %0"
               : "+v"(c) : "v"(a), "v"(b));
  return c;
#endif
}

__device__ inline short f2bf(float f) {            // RNE bf16
  union { float f; unsigned u; } v; v.f = f;
  unsigned u = v.u + 0x7fffu + ((v.u >> 16) & 1u);
  return (short)(u >> 16);
}
__device__ inline float lo16(unsigned u) { union { unsigned u; float f; } v; v.u = u << 16;        return v.f; }
__device__ inline float hi16(unsigned u) { union { unsigned u; float f; } v; v.u = u & 0xffff0000u; return v.f; }
__device__ inline unsigned pk2(float a, float b) { // fast-round pack 2xbf16
  union { float f; unsigned u; } x, y; x.f = a; y.f = b;
  return ((x.u + 0x8000u) >> 16) | ((y.u + 0x8000u) & 0xffff0000u);
}
// truncating pack 2xbf16 via one v_perm_b32 (lo=a, hi=b) — proven in R6
__device__ inline unsigned pktr(float a, float b) {
  union { float f; unsigned u; } x, y; x.f = a; y.f = b;
#if __has_builtin(__builtin_amdgcn_perm)
  return __builtin_amdgcn_perm(y.u, x.u, 0x07060302u);
#else
  return (x.u >> 16) | (y.u & 0xffff0000u);
#endif
}

// ---------------------------------------------------------------------------
// k_prep: bf16 weight copies (layouts unchanged: [o][c]) + dBN folding
// ---------------------------------------------------------------------------
__global__ __launch_bounds__(256) void k_prep(
    const float* __restrict__ qkv_w, const float* __restrict__ attn_w,
    const float* __restrict__ dbn_g, const float* __restrict__ dbn_b,
    const float* __restrict__ dbn_m, const float* __restrict__ dbn_v,
    short* __restrict__ wqb, short* __restrict__ wab,
    float* __restrict__ dsc, float* __restrict__ dsh)
{
  const int tid = blockIdx.x*256 + threadIdx.x;
  const int nthr = gridDim.x*256;
  for (int i = tid; i < QO_*C_; i += nthr) wqb[i] = f2bf(qkv_w[i]);
  for (int i = tid; i < DV_*DV_; i += nthr) wab[i] = f2bf(attn_w[i]);
  for (int i = tid; i < C_*V_; i += nthr) {
    float sc = dbn_g[i] * rsqrtf(dbn_v[i] + EPS_);
    dsc[i] = sc;
    dsh[i] = dbn_b[i] - dbn_m[i]*sc;
  }
}

// ---------------------------------------------------------------------------
// k_xt2: fused dBN + transpose  x[n][c][t][v] -> xtb[b=n*V+v][t][c] bf16
// ---------------------------------------------------------------------------
__global__ __launch_bounds__(256) void k_xt2(
    const float* __restrict__ x, const float* __restrict__ dsc,
    const float* __restrict__ dsh, short* __restrict__ xtb)
{
  const int n = blockIdx.x, tv0 = blockIdx.y * 125;
  __shared__ short ls[C_][126];
  for (int i = threadIdx.x; i < C_*125; i += 256) {
    int c = i / 125, j = i % 125;
    int cv = c*V_ + j % 25;                  // tv0 % 25 == 0
    ls[c][j] = f2bf(x[((size_t)n*C_ + c)*(T_*V_) + tv0 + j] * dsc[cv] + dsh[cv]);
  }
  __syncthreads();
  for (int i = threadIdx.x; i < 125*C_; i += 256) {
    int j = i >> 7, c = i & 127;
    int tv = tv0 + j, t = tv / 25, v = tv % 25;
    xtb[((size_t)(n*V_ + v)*T_ + t)*C_ + c] = ls[c][j];
  }
}

// ---------------------------------------------------------------------------
// k_qkv: bf16 MFMA GEMM  qkvb[b][o][t] = bf16(sum_c wqb[o][c]*xtb[b][t][c] + qkv_b[o])
// ---------------------------------------------------------------------------
__global__ __launch_bounds__(256) void k_qkv(
    const short* __restrict__ xtb, const short* __restrict__ wqb,
    const float* __restrict__ qkv_b, short* __restrict__ qkvb)
{
  const int b = blockIdx.x, t0 = blockIdx.y * 80;
  __shared__ short xs[80][136];            // 272B rows: <=2-way banks
  for (int i = threadIdx.x; i < 80*16; i += 256) {
    int tt = i >> 4, ch = i & 15, t = t0 + tt;
    short8 vv = {0,0,0,0,0,0,0,0};
    if (t < T_) vv = *(const short8*)&xtb[((size_t)b*T_ + t)*C_ + ch*8];
    *(short8*)&xs[tt][ch*8] = vv;
  }
  __syncthreads();
  const int wave = threadIdx.x >> 6, lane = threadIdx.x & 63;
  const int tl = lane & 15, g = lane >> 4;
  const int ob = wave * 48;

  bf16x4 afr[3][8];
  #pragma unroll
  for (int mt = 0; mt < 3; ++mt)
    #pragma unroll
    for (int ks = 0; ks < 8; ++ks)
      afr[mt][ks] = *(const bf16x4*)&wqb[(ob + mt*16 + tl)*C_ + ks*16 + g*4];

  const f32x4 zero = {0.f,0.f,0.f,0.f};
  f32x4 acc[3][5];
  #pragma unroll
  for (int mt = 0; mt < 3; ++mt)
    #pragma unroll
    for (int nt = 0; nt < 5; ++nt) acc[mt][nt] = zero;

  #pragma unroll
  for (int ks = 0; ks < 8; ++ks) {
    bf16x4 bfr[5];
    #pragma unroll
    for (int nt = 0; nt < 5; ++nt)
      bfr[nt] = *(const bf16x4*)&xs[nt*16 + tl][ks*16 + g*4];
    #pragma unroll
    for (int mt = 0; mt < 3; ++mt)
      #pragma unroll
      for (int nt = 0; nt < 5; ++nt)
        acc[mt][nt] = mfma16(afr[mt][ks], bfr[nt], acc[mt][nt]);
  }

  float bia[3][4];
  #pragma unroll
  for (int mt = 0; mt < 3; ++mt)
    #pragma unroll
    for (int r = 0; r < 4; ++r) bia[mt][r] = qkv_b[ob + mt*16 + g*4 + r];

  #pragma unroll
  for (int nt = 0; nt < 5; ++nt) {
    int tg = t0 + nt*16 + tl;
    if (tg >= T_) continue;
    #pragma unroll
    for (int mt = 0; mt < 3; ++mt) {
      int o = ob + mt*16 + g*4;
      short* dst = &qkvb[((size_t)b*QO_ + o)*T_ + tg];
      #pragma unroll
      for (int r = 0; r < 4; ++r)
        dst[r*T_] = f2bf(acc[mt][nt][r] + bia[mt][r]);
    }
  }
}

// ---------------------------------------------------------------------------
// k_attn: R5-proven structure (4 waves, rel on K=16 MFMA block-diagonal,
//   no-max softmax), plus:
//   - grid split: blockIdx.y in {0,1} owns 5 t-tiles -> wave critical path
//     2 tiles instead of 3 (load balance without odd wave counts)
//   - pktr (1x v_perm_b32) P-packing (numerically proven R6)
// ---------------------------------------------------------------------------
__global__ __launch_bounds__(256) void k_attn(
    const short* __restrict__ qkvb, const float* __restrict__ key_rel,
    short* __restrict__ o2b)
{
  const int bh = blockIdx.x;          // 0..3199
  const int b  = bh >> 3, h = bh & 7;
  const int ty = blockIdx.y;          // 0..1: t-tiles ty*5 .. ty*5+4
  __shared__ short kb[160][20];       // K[s][d], d4..15 zero     (6400 B)
  __shared__ short qb[160][20];       // Q[t][d]*0.5*log2e        (6400 B)
  __shared__ short ve[16][164];       // V^T[e][s]                (5248 B)
  __shared__ short krb[336*4];        // kr rows bf16x4, row m+16, zero guard (2688 B)
  const short* base = qkvb + (size_t)b*QO_*T_;
  const int tid = threadIdx.x;
  const float QSC = 0.5f * 1.44269504f;

  for (int i = tid; i < 4*160; i += 256) {
    int d = i / 160, s = i % 160;
    kb[s][d] = (s < T_) ? base[(DK_ + h*4 + d)*T_ + s] : (short)0;
  }
  for (int i = tid; i < 4*160; i += 256) {
    int d = i / 160, t = i % 160;
    short qv = (t < T_) ? base[(h*4 + d)*T_ + t] : (short)0;
    union { unsigned u; float f; } uf; uf.u = ((unsigned)(unsigned short)qv) << 16;
    qb[t][d] = f2bf(uf.f * QSC);
  }
  for (int i = tid; i < 160*12; i += 256) {   // zero d=4..15 pads
    int s = i / 12, j = i % 12 + 4;
    kb[s][j] = 0; qb[s][j] = 0;
  }
  for (int i = tid; i < 16*160; i += 256) {
    int e = i / 160, s = i % 160;
    ve[e][s] = (s < T_) ? base[(2*DK_ + h*16 + e)*T_ + s] : (short)0;
  }
  for (int i = tid; i < 336*4; i += 256) {    // bf16 kr table, row = m+16
    int m = (i >> 2) - 16;
    krb[i] = (m >= 0 && m < 2*T_-1) ? f2bf(key_rel[m*4 + (i & 3)]) : (short)0;
  }
  __syncthreads();

  const int wave = tid >> 6, lane = tid & 63;
  const int tl = lane & 15, g = lane >> 4, soff = g << 2;

  bf16x4 kfr[10], vfr[10];
  #pragma unroll
  for (int st = 0; st < 10; ++st) {
    kfr[st] = *(const bf16x4*)&kb[st*16 + tl][soff];   // A: row s, k=d
    vfr[st] = *(const bf16x4*)&ve[tl][st*16 + soff];   // A: row e, k=s
  }

  const f32x4 zero = {0.f, 0.f, 0.f, 0.f};
  const bf16x4 zerob = {0, 0, 0, 0};
  const bool act = (g == (tl & 3));   // lane holds B' nonzeros only here
  const int kca = tl >> 2;            // ...and only in this K-chunk

  for (int tlp = wave; tlp < 5; tlp += 4) {
    const int tt = ty*5 + tlp;
    const int t0 = tt*16, tg = t0 + tl;
    const bf16x4 qfr = *(const bf16x4*)&qb[tg][soff];  // B: col t, k=d
    f32x4 c[10];
    #pragma unroll
    for (int st = 0; st < 10; ++st) c[st] = mfma16(kfr[st], qfr, zero);

    // B' fragments: q[t0+tl][0..3] on the diagonal lane/chunk, else 0
    union { unsigned u[2]; bf16x4 v; } bqu;
    bqu.u[0] = *(const unsigned*)&qb[tg][0];
    bqu.u[1] = *(const unsigned*)&qb[tg][2];
    bf16x4 brel[4];
    #pragma unroll
    for (int kc = 0; kc < 4; ++kc)
      brel[kc] = (act && kc == kca) ? bqu.v : zerob;

    // A' gather base: row = (tl - g + 165 - t0) + st*16 - kc*4
    const bf16x4* krp = ((const bf16x4*)krb) + (tl - g + 165 - t0);
    #pragma unroll
    for (int st = 0; st < 10; ++st)
      #pragma unroll
      for (int kc = 0; kc < 4; ++kc)
        c[st] = mfma16(krp[st*16 - kc*4], brel[kc], c[st]);

    // mask padded s rows (s = 144 + soff + i >= 150): exp2(-3e38) -> 0
    #pragma unroll
    for (int i = 0; i < 4; ++i)
      if (soff + i >= 6) c[9][i] = -3.0e38f;

    float l = 0.f;
    f32x4 acc = zero;
    #pragma unroll
    for (int st = 0; st < 10; ++st) {
      float p0 = __builtin_exp2f(c[st][0]);
      float p1 = __builtin_exp2f(c[st][1]);
      float p2 = __builtin_exp2f(c[st][2]);
      float p3 = __builtin_exp2f(c[st][3]);
      l += (p0 + p1) + (p2 + p3);
      union { unsigned u[2]; bf16x4 v; } pf;
      pf.u[0] = pktr(p0, p1); pf.u[1] = pktr(p2, p3);
      acc = mfma16(vfr[st], pf.v, acc);
    }
    l += __shfl_xor(l, 16);
    l += __shfl_xor(l, 32);
    const float inv = __builtin_amdgcn_rcpf(l);

    if (tg < T_) {
      unsigned u0 = pk2(acc[0]*inv, acc[1]*inv);
      unsigned u1 = pk2(acc[2]*inv, acc[3]*inv);
      *(uint2*)&o2b[((size_t)b*T_ + tg)*DV_ + h*16 + soff] = make_uint2(u0, u1);
    }
  }
}

// ---------------------------------------------------------------------------
// k_proj: bf16 MFMA GEMM  projb[b][o][t] = bf16(sum_c wab[o][c]*o2b[b][t][c] + attn_b[o])
// ---------------------------------------------------------------------------
__global__ __launch_bounds__(256) void k_proj(
    const short* __restrict__ o2b, const short* __restrict__ wab,
    const float* __restrict__ attn_b, short* __restrict__ projb)
{
  const int b = blockIdx.x, t0 = blockIdx.y * 80;
  __shared__ short xs[80][136];
  for (int i = threadIdx.x; i < 80*16; i += 256) {
    int tt = i >> 4, ch = i & 15, t = t0 + tt;
    short8 vv = {0,0,0,0,0,0,0,0};
    if (t < T_) vv = *(const short8*)&o2b[((size_t)b*T_ + t)*DV_ + ch*8];
    *(short8*)&xs[tt][ch*8] = vv;
  }
  __syncthreads();
  const int wave = threadIdx.x >> 6, lane = threadIdx.x & 63;
  const int tl = lane & 15, g = lane >> 4;
  const int ob = wave * 32;

  bf16x4 afr[2][8];
  #pragma unroll
  for (int mt = 0; mt < 2; ++mt)
    #pragma unroll
    for (int ks = 0; ks < 8; ++ks)
      afr[mt][ks] = *(const bf16x4*)&wab[(ob + mt*16 + tl)*DV_ + ks*16 + g*4];

  const f32x4 zero = {0.f,0.f,0.f,0.f};
  f32x4 acc[2][5];
  #pragma unroll
  for (int mt = 0; mt < 2; ++mt)
    #pragma unroll
    for (int nt = 0; nt < 5; ++nt) acc[mt][nt] = zero;

  #pragma unroll
  for (int ks = 0; ks < 8; ++ks) {
    bf16x4 bfr[5];
    #pragma unroll
    for (int nt = 0; nt < 5; ++nt)
      bfr[nt] = *(const bf16x4*)&xs[nt*16 + tl][ks*16 + g*4];
    #pragma unroll
    for (int mt = 0; mt < 2; ++mt)
      #pragma unroll
      for (int nt = 0; nt < 5; ++nt)
        acc[mt][nt] = mfma16(afr[mt][ks], bfr[nt], acc[mt][nt]);
  }

  float bia[2][4];
  #pragma unroll
  for (int mt = 0; mt < 2; ++mt)
    #pragma unroll
    for (int r = 0; r < 4; ++r) bia[mt][r] = attn_b[ob + mt*16 + g*4 + r];

  #pragma unroll
  for (int nt = 0; nt < 5; ++nt) {
    int tg = t0 + nt*16 + tl;
    if (tg >= T_) continue;
    #pragma unroll
    for (int mt = 0; mt < 2; ++mt) {
      int o = ob + mt*16 + g*4;
      short* dst = &projb[((size_t)b*DV_ + o)*T_ + tg];
      #pragma unroll
      for (int r = 0; r < 4; ++r)
        dst[r*T_] = f2bf(acc[mt][nt][r] + bia[mt][r]);
    }
  }
}

// ---------------------------------------------------------------------------
// k_final: transpose projb[b][o][t] -> out[n][o][t][v], + residual + BN + ReLU
// ---------------------------------------------------------------------------
__global__ __launch_bounds__(256) void k_final(
    const short* __restrict__ projb, const float* __restrict__ x,
    const float* __restrict__ bn_g, const float* __restrict__ bn_b,
    const float* __restrict__ bn_m, const float* __restrict__ bn_v,
    float* __restrict__ out)
{
  const int n = blockIdx.x, o = blockIdx.y;
  __shared__ short ls[V_*T_];
  for (int i = threadIdx.x; i < V_*T_; i += 256) {
    int v = i / T_, t = i % T_;
    ls[i] = projb[((size_t)(n*V_ + v)*DV_ + o)*T_ + t];
  }
  __syncthreads();
  const float sc = bn_g[o] * rsqrtf(bn_v[o] + EPS_);
  const float sh = bn_b[o] - bn_m[o]*sc;
  const size_t base = ((size_t)n*C_ + o)*(T_*V_);
  for (int j = threadIdx.x; j < T_*V_; j += 256) {
    int t = j / V_, v = j % V_;
    float pv = lo16((unsigned)(unsigned short)ls[v*T_ + t]);
    float r = (pv + x[base + j]) * sc + sh;
    out[base + j] = fmaxf(r, 0.f);
  }
}

// ---------------------------------------------------------------------------
extern "C" void kernel_launch(void* const* d_in, const int* in_sizes, int n_in,
                              void* d_out, int out_size, void* d_ws, size_t ws_size,
                              hipStream_t stream) {
  const float* x       = (const float*)d_in[0];
  const float* qkv_w   = (const float*)d_in[1];
  const float* qkv_b   = (const float*)d_in[2];
  const float* key_rel = (const float*)d_in[3];
  const float* attn_w  = (const float*)d_in[4];
  const float* attn_b  = (const float*)d_in[5];
  const float* dbn_g   = (const float*)d_in[6];
  const float* dbn_b   = (const float*)d_in[7];
  const float* dbn_m   = (const float*)d_in[8];
  const float* dbn_v   = (const float*)d_in[9];
  const float* bn_g    = (const float*)d_in[10];
  const float* bn_b    = (const float*)d_in[11];
  const float* bn_m    = (const float*)d_in[12];
  const float* bn_v    = (const float*)d_in[13];

  // ws layout: xtb/o2b | qkvb | proj region (bf16 uses half) | consts
  short* xtb  = (short*)d_ws;                          // 7.68M shorts, reused as o2b
  short* o2b  = xtb;
  short* qkvb = xtb + (size_t)B_*C_*T_;                // 11.52M shorts
  float* projf = (float*)(qkvb + (size_t)B_*QO_*T_);   // region reserved as before
  short* projb = (short*)projf;                        // bf16 actually used
  float* dsc  = projf + (size_t)B_*DV_*T_;             // 3200
  float* dsh  = dsc + C_*V_;                           // 3200
  short* wqb  = (short*)(dsh + C_*V_);                 // 24576 shorts
  short* wab  = wqb + QO_*C_;                          // 16384 shorts
  float* outp = (float*)d_out;

  k_prep<<<32, 256, 0, stream>>>(qkv_w, attn_w, dbn_g, dbn_b, dbn_m, dbn_v,
                                 wqb, wab, dsc, dsh);
  k_xt2<<<dim3(N_, 30), 256, 0, stream>>>(x, dsc, dsh, xtb);
  k_qkv<<<dim3(B_, 2), 256, 0, stream>>>(xtb, wqb, qkv_b, qkvb);
  k_attn<<<dim3(B_*NH_, 2), 256, 0, stream>>>(qkvb, key_rel, o2b);
  k_proj<<<dim3(B_, 2), 256, 0, stream>>>(o2b, wab, attn_b, projb);
  k_final<<<dim3(N_, DV_), 256, 0, stream>>>(projb, x, bn_g, bn_b, bn_m, bn_v, outp);
}

// Round 9
// 169.028 us; speedup vs baseline: 1.0478x; 1.0478x over previous
//
#include <hip/hip_runtime.h>
#include <math.h>

#define N_   16
#define C_   128
#define T_   150
#define V_   25
#define NH_  8
#define DK_  32
#define DV_  128
#define B_   400      // N_*V_
#define QO_  192      // 2*DK_+DV_
#define EPS_ 1e-5f

typedef __attribute__((ext_vector_type(4))) short bf16x4;
typedef __attribute__((ext_vector_type(4))) float f32x4;
typedef __attribute__((ext_vector_type(8))) short short8;

__device__ inline f32x4 mfma16(bf16x4 a, bf16x4 b, f32x4 c) {
#if __has_builtin(__builtin_amdgcn_mfma_f32_16x16x16bf16_1k)
  return __builtin_amdgcn_mfma_f32_16x16x16bf16_1k(a, b, c, 0, 0, 0);
#else
  asm volatile("v_mfma_f32_16x16x16_bf16 %0, %1, %2, %0"
               : "+v"(c) : "v"(a), "v"(b));
  return c;
#endif
}

__device__ inline short f2bf(float f) {            // RNE bf16
  union { float f; unsigned u; } v; v.f = f;
  unsigned u = v.u + 0x7fffu + ((v.u >> 16) & 1u);
  return (short)(u >> 16);
}
__device__ inline float lo16(unsigned u) { union { unsigned u; float f; } v; v.u = u << 16;        return v.f; }
__device__ inline float hi16(unsigned u) { union { unsigned u; float f; } v; v.u = u & 0xffff0000u; return v.f; }
__device__ inline unsigned pk2(float a, float b) { // fast-round pack 2xbf16
  union { float f; unsigned u; } x, y; x.f = a; y.f = b;
  return ((x.u + 0x8000u) >> 16) | ((y.u + 0x8000u) & 0xffff0000u);
}
// truncating pack 2xbf16 via one v_perm_b32 (lo=a, hi=b) — proven R6/R8
__device__ inline unsigned pktr(float a, float b) {
  union { float f; unsigned u; } x, y; x.f = a; y.f = b;
#if __has_builtin(__builtin_amdgcn_perm)
  return __builtin_amdgcn_perm(y.u, x.u, 0x07060302u);
#else
  return (x.u >> 16) | (y.u & 0xffff0000u);
#endif
}

// ---------------------------------------------------------------------------
// k_prep: bf16 weight copies (layouts unchanged: [o][c]) + dBN folding
// ---------------------------------------------------------------------------
__global__ __launch_bounds__(256) void k_prep(
    const float* __restrict__ qkv_w, const float* __restrict__ attn_w,
    const float* __restrict__ dbn_g, const float* __restrict__ dbn_b,
    const float* __restrict__ dbn_m, const float* __restrict__ dbn_v,
    short* __restrict__ wqb, short* __restrict__ wab,
    float* __restrict__ dsc, float* __restrict__ dsh)
{
  const int tid = blockIdx.x*256 + threadIdx.x;
  const int nthr = gridDim.x*256;
  for (int i = tid; i < QO_*C_; i += nthr) wqb[i] = f2bf(qkv_w[i]);
  for (int i = tid; i < DV_*DV_; i += nthr) wab[i] = f2bf(attn_w[i]);
  for (int i = tid; i < C_*V_; i += nthr) {
    float sc = dbn_g[i] * rsqrtf(dbn_v[i] + EPS_);
    dsc[i] = sc;
    dsh[i] = dbn_b[i] - dbn_m[i]*sc;
  }
}

// ---------------------------------------------------------------------------
// k_xt2: fused dBN + transpose  x[n][c][t][v] -> xtb[b=n*V+v][t][c] bf16
// ---------------------------------------------------------------------------
__global__ __launch_bounds__(256) void k_xt2(
    const float* __restrict__ x, const float* __restrict__ dsc,
    const float* __restrict__ dsh, short* __restrict__ xtb)
{
  const int n = blockIdx.x, tv0 = blockIdx.y * 125;
  __shared__ short ls[C_][126];
  for (int i = threadIdx.x; i < C_*125; i += 256) {
    int c = i / 125, j = i % 125;
    int cv = c*V_ + j % 25;                  // tv0 % 25 == 0
    ls[c][j] = f2bf(x[((size_t)n*C_ + c)*(T_*V_) + tv0 + j] * dsc[cv] + dsh[cv]);
  }
  __syncthreads();
  for (int i = threadIdx.x; i < 125*C_; i += 256) {
    int j = i >> 7, c = i & 127;
    int tv = tv0 + j, t = tv / 25, v = tv % 25;
    xtb[((size_t)(n*V_ + v)*T_ + t)*C_ + c] = ls[c][j];
  }
}

// ---------------------------------------------------------------------------
// k_qkv: bf16 MFMA GEMM. q channels (o<DK) are pre-scaled by 0.5*log2e so
// k_attn needs no Q conversion pass.
// ---------------------------------------------------------------------------
__global__ __launch_bounds__(256) void k_qkv(
    const short* __restrict__ xtb, const short* __restrict__ wqb,
    const float* __restrict__ qkv_b, short* __restrict__ qkvb)
{
  const int b = blockIdx.x, t0 = blockIdx.y * 80;
  __shared__ short xs[80][136];            // 272B rows: <=2-way banks
  for (int i = threadIdx.x; i < 80*16; i += 256) {
    int tt = i >> 4, ch = i & 15, t = t0 + tt;
    short8 vv = {0,0,0,0,0,0,0,0};
    if (t < T_) vv = *(const short8*)&xtb[((size_t)b*T_ + t)*C_ + ch*8];
    *(short8*)&xs[tt][ch*8] = vv;
  }
  __syncthreads();
  const int wave = threadIdx.x >> 6, lane = threadIdx.x & 63;
  const int tl = lane & 15, g = lane >> 4;
  const int ob = wave * 48;

  bf16x4 afr[3][8];
  #pragma unroll
  for (int mt = 0; mt < 3; ++mt)
    #pragma unroll
    for (int ks = 0; ks < 8; ++ks)
      afr[mt][ks] = *(const bf16x4*)&wqb[(ob + mt*16 + tl)*C_ + ks*16 + g*4];

  const f32x4 zero = {0.f,0.f,0.f,0.f};
  f32x4 acc[3][5];
  #pragma unroll
  for (int mt = 0; mt < 3; ++mt)
    #pragma unroll
    for (int nt = 0; nt < 5; ++nt) acc[mt][nt] = zero;

  #pragma unroll
  for (int ks = 0; ks < 8; ++ks) {
    bf16x4 bfr[5];
    #pragma unroll
    for (int nt = 0; nt < 5; ++nt)
      bfr[nt] = *(const bf16x4*)&xs[nt*16 + tl][ks*16 + g*4];
    #pragma unroll
    for (int mt = 0; mt < 3; ++mt)
      #pragma unroll
      for (int nt = 0; nt < 5; ++nt)
        acc[mt][nt] = mfma16(afr[mt][ks], bfr[nt], acc[mt][nt]);
  }

  float bia[3][4], scm[3];
  #pragma unroll
  for (int mt = 0; mt < 3; ++mt) {
    scm[mt] = (ob + mt*16 < DK_) ? (0.5f*1.44269504f) : 1.f;
    #pragma unroll
    for (int r = 0; r < 4; ++r) bia[mt][r] = qkv_b[ob + mt*16 + g*4 + r];
  }

  #pragma unroll
  for (int nt = 0; nt < 5; ++nt) {
    int tg = t0 + nt*16 + tl;
    if (tg >= T_) continue;
    #pragma unroll
    for (int mt = 0; mt < 3; ++mt) {
      int o = ob + mt*16 + g*4;
      short* dst = &qkvb[((size_t)b*QO_ + o)*T_ + tg];
      #pragma unroll
      for (int r = 0; r < 4; ++r)
        dst[r*T_] = f2bf((acc[mt][nt][r] + bia[mt][r]) * scm[mt]);
    }
  }
}

// ---------------------------------------------------------------------------
// k_attn: staging-free. K/V/Q fragments loaded global->register directly
// (LDS staging was ~2/3 of kernel time, proven by R8's 2x-staging probe).
// Only the kr gather table stays in LDS. Q arrives pre-scaled from k_qkv.
// rel on K=16 MFMA block-diagonal (proven R5); no-max softmax; pktr packing.
// blockIdx.y splits the 10 t-tiles 5/5 -> 2-tile critical path per wave.
// ---------------------------------------------------------------------------
__global__ __launch_bounds__(256) void k_attn(
    const short* __restrict__ qkvb, const float* __restrict__ key_rel,
    short* __restrict__ o2b)
{
  const int bh = blockIdx.x;          // 0..3199
  const int b  = bh >> 3, h = bh & 7;
  const int ty = blockIdx.y;          // 0..1: t-tiles ty*5 .. ty*5+4
  __shared__ short krb[336*4];        // kr rows bf16x4, row m+16, zero guard (2688 B)
  const short* base = qkvb + (size_t)b*QO_*T_;
  const int tid = threadIdx.x;

  for (int i = tid; i < 336*4; i += 256) {    // bf16 kr table, row = m+16
    int m = (i >> 2) - 16;
    krb[i] = (m >= 0 && m < 2*T_-1) ? f2bf(key_rel[m*4 + (i & 3)]) : (short)0;
  }
  __syncthreads();

  const int wave = tid >> 6, lane = tid & 63;
  const int tl = lane & 15, g = lane >> 4, soff = g << 2;

  const bf16x4 zerob = {0, 0, 0, 0};
  const f32x4 zero = {0.f, 0.f, 0.f, 0.f};

  // K fragments: A row s = st*16+tl, k = d (d<4 real; g>0 lanes were zero-pad)
  bf16x4 kfr[10];
  #pragma unroll
  for (int st = 0; st < 10; ++st) kfr[st] = zerob;
  if (g == 0) {
    const short* kb0 = base + (size_t)(DK_ + h*4)*T_;
    #pragma unroll
    for (int st = 0; st < 10; ++st) {
      int s = st*16 + tl;
      if (s < T_) {
        bf16x4 kf;
        #pragma unroll
        for (int j = 0; j < 4; ++j) kf[j] = kb0[j*T_ + s];
        kfr[st] = kf;
      }
    }
  }

  // V fragments: A row e = tl, k = s = st*16+soff+j (contiguous in s)
  bf16x4 vfr[10];
  const short* vb0 = base + (size_t)(2*DK_ + h*16 + tl)*T_;
  #pragma unroll
  for (int st = 0; st < 9; ++st) {
    int s0 = st*16 + soff;
    union { unsigned u[2]; bf16x4 v; } vv;
    vv.u[0] = *(const unsigned*)&vb0[s0];
    vv.u[1] = *(const unsigned*)&vb0[s0 + 2];
    vfr[st] = vv.v;
  }
  {
    bf16x4 vf = zerob;                 // st=9: predicate s<150 (NaN hygiene)
    #pragma unroll
    for (int j = 0; j < 4; ++j) {
      int s = 144 + soff + j;
      if (s < T_) vf[j] = vb0[s];
    }
    vfr[9] = vf;
  }

  const bool act = (g == (tl & 3));   // lane holds B' nonzeros only here
  const int kca = tl >> 2;            // ...and only in this K-chunk
  const short* qb0 = base + (size_t)h*4*T_;

  for (int tlp = wave; tlp < 5; tlp += 4) {
    const int tt = ty*5 + tlp;
    const int t0 = tt*16, tg = t0 + tl;

    // q row tg (pre-scaled): 4 strided scalar loads on the lanes that use them
    short qv0 = 0, qv1 = 0, qv2 = 0, qv3 = 0;
    if (g == 0 || act) {
      qv0 = qb0[tg];        qv1 = qb0[T_ + tg];
      qv2 = qb0[2*T_ + tg]; qv3 = qb0[3*T_ + tg];
    }
    bf16x4 qfr = zerob;                 // B: col t, k=d (g==0 slice only)
    if (g == 0) { qfr[0] = qv0; qfr[1] = qv1; qfr[2] = qv2; qfr[3] = qv3; }

    f32x4 c[10];
    #pragma unroll
    for (int st = 0; st < 10; ++st) c[st] = mfma16(kfr[st], qfr, zero);

    // B' fragments: q row on the diagonal lane/chunk, else 0
    union { unsigned u[2]; bf16x4 v; } bqu;
    bqu.u[0] = (unsigned)(unsigned short)qv0 | ((unsigned)(unsigned short)qv1 << 16);
    bqu.u[1] = (unsigned)(unsigned short)qv2 | ((unsigned)(unsigned short)qv3 << 16);
    bf16x4 brel[4];
    #pragma unroll
    for (int kc = 0; kc < 4; ++kc)
      brel[kc] = (act && kc == kca) ? bqu.v : zerob;

    // A' gather base: row = (tl - g + 165 - t0) + st*16 - kc*4
    const bf16x4* krp = ((const bf16x4*)krb) + (tl - g + 165 - t0);
    #pragma unroll
    for (int st = 0; st < 10; ++st)
      #pragma unroll
      for (int kc = 0; kc < 4; ++kc)
        c[st] = mfma16(krp[st*16 - kc*4], brel[kc], c[st]);

    // mask padded s rows (s = 144 + soff + i >= 150): exp2(-3e38) -> 0
    #pragma unroll
    for (int i = 0; i < 4; ++i)
      if (soff + i >= 6) c[9][i] = -3.0e38f;

    float l = 0.f;
    f32x4 acc = zero;
    #pragma unroll
    for (int st = 0; st < 10; ++st) {
      float p0 = __builtin_exp2f(c[st][0]);
      float p1 = __builtin_exp2f(c[st][1]);
      float p2 = __builtin_exp2f(c[st][2]);
      float p3 = __builtin_exp2f(c[st][3]);
      l += (p0 + p1) + (p2 + p3);
      union { unsigned u[2]; bf16x4 v; } pf;
      pf.u[0] = pktr(p0, p1); pf.u[1] = pktr(p2, p3);
      acc = mfma16(vfr[st], pf.v, acc);
    }
    l += __shfl_xor(l, 16);
    l += __shfl_xor(l, 32);
    const float inv = __builtin_amdgcn_rcpf(l);

    if (tg < T_) {
      unsigned u0 = pk2(acc[0]*inv, acc[1]*inv);
      unsigned u1 = pk2(acc[2]*inv, acc[3]*inv);
      *(uint2*)&o2b[((size_t)b*T_ + tg)*DV_ + h*16 + soff] = make_uint2(u0, u1);
    }
  }
}

// ---------------------------------------------------------------------------
// k_proj: bf16 MFMA GEMM  projb[b][o][t] = bf16(sum_c wab[o][c]*o2b[b][t][c] + attn_b[o])
// ---------------------------------------------------------------------------
__global__ __launch_bounds__(256) void k_proj(
    const short* __restrict__ o2b, const short* __restrict__ wab,
    const float* __restrict__ attn_b, short* __restrict__ projb)
{
  const int b = blockIdx.x, t0 = blockIdx.y * 80;
  __shared__ short xs[80][136];
  for (int i = threadIdx.x; i < 80*16; i += 256) {
    int tt = i >> 4, ch = i & 15, t = t0 + tt;
    short8 vv = {0,0,0,0,0,0,0,0};
    if (t < T_) vv = *(const short8*)&o2b[((size_t)b*T_ + t)*DV_ + ch*8];
    *(short8*)&xs[tt][ch*8] = vv;
  }
  __syncthreads();
  const int wave = threadIdx.x >> 6, lane = threadIdx.x & 63;
  const int tl = lane & 15, g = lane >> 4;
  const int ob = wave * 32;

  bf16x4 afr[2][8];
  #pragma unroll
  for (int mt = 0; mt < 2; ++mt)
    #pragma unroll
    for (int ks = 0; ks < 8; ++ks)
      afr[mt][ks] = *(const bf16x4*)&wab[(ob + mt*16 + tl)*DV_ + ks*16 + g*4];

  const f32x4 zero = {0.f,0.f,0.f,0.f};
  f32x4 acc[2][5];
  #pragma unroll
  for (int mt = 0; mt < 2; ++mt)
    #pragma unroll
    for (int nt = 0; nt < 5; ++nt) acc[mt][nt] = zero;

  #pragma unroll
  for (int ks = 0; ks < 8; ++ks) {
    bf16x4 bfr[5];
    #pragma unroll
    for (int nt = 0; nt < 5; ++nt)
      bfr[nt] = *(const bf16x4*)&xs[nt*16 + tl][ks*16 + g*4];
    #pragma unroll
    for (int mt = 0; mt < 2; ++mt)
      #pragma unroll
      for (int nt = 0; nt < 5; ++nt)
        acc[mt][nt] = mfma16(afr[mt][ks], bfr[nt], acc[mt][nt]);
  }

  float bia[2][4];
  #pragma unroll
  for (int mt = 0; mt < 2; ++mt)
    #pragma unroll
    for (int r = 0; r < 4; ++r) bia[mt][r] = attn_b[ob + mt*16 + g*4 + r];

  #pragma unroll
  for (int nt = 0; nt < 5; ++nt) {
    int tg = t0 + nt*16 + tl;
    if (tg >= T_) continue;
    #pragma unroll
    for (int mt = 0; mt < 2; ++mt) {
      int o = ob + mt*16 + g*4;
      short* dst = &projb[((size_t)b*DV_ + o)*T_ + tg];
      #pragma unroll
      for (int r = 0; r < 4; ++r)
        dst[r*T_] = f2bf(acc[mt][nt][r] + bia[mt][r]);
    }
  }
}

// ---------------------------------------------------------------------------
// k_final: transpose projb[b][o][t] -> out[n][o][t][v], + residual + BN + ReLU
// ---------------------------------------------------------------------------
__global__ __launch_bounds__(256) void k_final(
    const short* __restrict__ projb, const float* __restrict__ x,
    const float* __restrict__ bn_g, const float* __restrict__ bn_b,
    const float* __restrict__ bn_m, const float* __restrict__ bn_v,
    float* __restrict__ out)
{
  const int n = blockIdx.x, o = blockIdx.y;
  __shared__ short ls[V_*T_];
  for (int i = threadIdx.x; i < V_*T_; i += 256) {
    int v = i / T_, t = i % T_;
    ls[i] = projb[((size_t)(n*V_ + v)*DV_ + o)*T_ + t];
  }
  __syncthreads();
  const float sc = bn_g[o] * rsqrtf(bn_v[o] + EPS_);
  const float sh = bn_b[o] - bn_m[o]*sc;
  const size_t base = ((size_t)n*C_ + o)*(T_*V_);
  for (int j = threadIdx.x; j < T_*V_; j += 256) {
    int t = j / V_, v = j % V_;
    float pv = lo16((unsigned)(unsigned short)ls[v*T_ + t]);
    float r = (pv + x[base + j]) * sc + sh;
    out[base + j] = fmaxf(r, 0.f);
  }
}

// ---------------------------------------------------------------------------
extern "C" void kernel_launch(void* const* d_in, const int* in_sizes, int n_in,
                              void* d_out, int out_size, void* d_ws, size_t ws_size,
                              hipStream_t stream) {
  const float* x       = (const float*)d_in[0];
  const float* qkv_w   = (const float*)d_in[1];
  const float* qkv_b   = (const float*)d_in[2];
  const float* key_rel = (const float*)d_in[3];
  const float* attn_w  = (const float*)d_in[4];
  const float* attn_b  = (const float*)d_in[5];
  const float* dbn_g   = (const float*)d_in[6];
  const float* dbn_b   = (const float*)d_in[7];
  const float* dbn_m   = (const float*)d_in[8];
  const float* dbn_v   = (const float*)d_in[9];
  const float* bn_g    = (const float*)d_in[10];
  const float* bn_b    = (const float*)d_in[11];
  const float* bn_m    = (const float*)d_in[12];
  const float* bn_v    = (const float*)d_in[13];

  // ws layout: xtb/o2b | qkvb | proj region (bf16 uses half) | consts
  short* xtb  = (short*)d_ws;                          // 7.68M shorts, reused as o2b
  short* o2b  = xtb;
  short* qkvb = xtb + (size_t)B_*C_*T_;                // 11.52M shorts
  float* projf = (float*)(qkvb + (size_t)B_*QO_*T_);   // region reserved as before
  short* projb = (short*)projf;                        // bf16 actually used
  float* dsc  = projf + (size_t)B_*DV_*T_;             // 3200
  float* dsh  = dsc + C_*V_;                           // 3200
  short* wqb  = (short*)(dsh + C_*V_);                 // 24576 shorts
  short* wab  = wqb + QO_*C_;                          // 16384 shorts
  float* outp = (float*)d_out;

  k_prep<<<32, 256, 0, stream>>>(qkv_w, attn_w, dbn_g, dbn_b, dbn_m, dbn_v,
                                 wqb, wab, dsc, dsh);
  k_xt2<<<dim3(N_, 30), 256, 0, stream>>>(x, dsc, dsh, xtb);
  k_qkv<<<dim3(B_, 2), 256, 0, stream>>>(xtb, wqb, qkv_b, qkvb);
  k_attn<<<dim3(B_*NH_, 2), 256, 0, stream>>>(qkvb, key_rel, o2b);
  k_proj<<<dim3(B_, 2), 256, 0, stream>>>(o2b, wab, attn_b, projb);
  k_final<<<dim3(N_, DV_), 256, 0, stream>>>(projb, x, bn_g, bn_b, bn_m, bn_v, outp);
}

// Round 10
// 127.180 us; speedup vs baseline: 1.3926x; 1.3290x over previous
//
#include <hip/hip_runtime.h>
#include <math.h>

#define N_   16
#define C_   128
#define T_   150
#define V_   25
#define NH_  8
#define DK_  32
#define DV_  128
#define B_   400      // N_*V_
#define QO_  192      // 2*DK_+DV_
#define EPS_ 1e-5f

typedef __attribute__((ext_vector_type(4))) short bf16x4;
typedef __attribute__((ext_vector_type(4))) float f32x4;
typedef __attribute__((ext_vector_type(8))) short short8;

__device__ inline f32x4 mfma16(bf16x4 a, bf16x4 b, f32x4 c) {
#if __has_builtin(__builtin_amdgcn_mfma_f32_16x16x16bf16_1k)
  return __builtin_amdgcn_mfma_f32_16x16x16bf16_1k(a, b, c, 0, 0, 0);
#else
  asm volatile("v_mfma_f32_16x16x16_bf16 %0, %1, %2, %0"
               : "+v"(c) : "v"(a), "v"(b));
  return c;
#endif
}

__device__ inline short f2bf(float f) {            // RNE bf16
  union { float f; unsigned u; } v; v.f = f;
  unsigned u = v.u + 0x7fffu + ((v.u >> 16) & 1u);
  return (short)(u >> 16);
}
__device__ inline float lo16(unsigned u) { union { unsigned u; float f; } v; v.u = u << 16;        return v.f; }
__device__ inline float hi16(unsigned u) { union { unsigned u; float f; } v; v.u = u & 0xffff0000u; return v.f; }
__device__ inline unsigned pk2(float a, float b) { // fast-round pack 2xbf16
  union { float f; unsigned u; } x, y; x.f = a; y.f = b;
  return ((x.u + 0x8000u) >> 16) | ((y.u + 0x8000u) & 0xffff0000u);
}
// truncating pack 2xbf16 via one v_perm_b32 (lo=a, hi=b) — proven R6/R8
__device__ inline unsigned pktr(float a, float b) {
  union { float f; unsigned u; } x, y; x.f = a; y.f = b;
#if __has_builtin(__builtin_amdgcn_perm)
  return __builtin_amdgcn_perm(y.u, x.u, 0x07060302u);
#else
  return (x.u >> 16) | (y.u & 0xffff0000u);
#endif
}

// ---------------------------------------------------------------------------
// k_prep: bf16 weight copies + dBN folding + bf16 key_rel gather table
// ---------------------------------------------------------------------------
__global__ __launch_bounds__(256) void k_prep(
    const float* __restrict__ qkv_w, const float* __restrict__ attn_w,
    const float* __restrict__ dbn_g, const float* __restrict__ dbn_b,
    const float* __restrict__ dbn_m, const float* __restrict__ dbn_v,
    const float* __restrict__ key_rel,
    short* __restrict__ wqb, short* __restrict__ wab,
    short* __restrict__ krbg,
    float* __restrict__ dsc, float* __restrict__ dsh)
{
  const int tid = blockIdx.x*256 + threadIdx.x;
  const int nthr = gridDim.x*256;
  for (int i = tid; i < QO_*C_; i += nthr) wqb[i] = f2bf(qkv_w[i]);
  for (int i = tid; i < DV_*DV_; i += nthr) wab[i] = f2bf(attn_w[i]);
  for (int i = tid; i < 336*4; i += nthr) {   // bf16 kr table, row = m+16, guards
    int m = (i >> 2) - 16;
    krbg[i] = (m >= 0 && m < 2*T_-1) ? f2bf(key_rel[m*4 + (i & 3)]) : (short)0;
  }
  for (int i = tid; i < C_*V_; i += nthr) {
    float sc = dbn_g[i] * rsqrtf(dbn_v[i] + EPS_);
    dsc[i] = sc;
    dsh[i] = dbn_b[i] - dbn_m[i]*sc;
  }
}

// ---------------------------------------------------------------------------
// k_xt2: fused dBN + transpose  x[n][c][t][v] -> xtb[b=n*V+v][t][c] bf16
// ---------------------------------------------------------------------------
__global__ __launch_bounds__(256) void k_xt2(
    const float* __restrict__ x, const float* __restrict__ dsc,
    const float* __restrict__ dsh, short* __restrict__ xtb)
{
  const int n = blockIdx.x, tv0 = blockIdx.y * 125;
  __shared__ short ls[C_][126];
  for (int i = threadIdx.x; i < C_*125; i += 256) {
    int c = i / 125, j = i % 125;
    int cv = c*V_ + j % 25;                  // tv0 % 25 == 0
    ls[c][j] = f2bf(x[((size_t)n*C_ + c)*(T_*V_) + tv0 + j] * dsc[cv] + dsh[cv]);
  }
  __syncthreads();
  for (int i = threadIdx.x; i < 125*C_; i += 256) {
    int j = i >> 7, c = i & 127;
    int tv = tv0 + j, t = tv / 25, v = tv % 25;
    xtb[((size_t)(n*V_ + v)*T_ + t)*C_ + c] = ls[c][j];
  }
}

// ---------------------------------------------------------------------------
// k_qkv: bf16 MFMA GEMM. q channels (o<DK) pre-scaled by 0.5*log2e (R9-proven)
// ---------------------------------------------------------------------------
__global__ __launch_bounds__(256) void k_qkv(
    const short* __restrict__ xtb, const short* __restrict__ wqb,
    const float* __restrict__ qkv_b, short* __restrict__ qkvb)
{
  const int b = blockIdx.x, t0 = blockIdx.y * 80;
  __shared__ short xs[80][136];            // 272B rows: <=2-way banks
  for (int i = threadIdx.x; i < 80*16; i += 256) {
    int tt = i >> 4, ch = i & 15, t = t0 + tt;
    short8 vv = {0,0,0,0,0,0,0,0};
    if (t < T_) vv = *(const short8*)&xtb[((size_t)b*T_ + t)*C_ + ch*8];
    *(short8*)&xs[tt][ch*8] = vv;
  }
  __syncthreads();
  const int wave = threadIdx.x >> 6, lane = threadIdx.x & 63;
  const int tl = lane & 15, g = lane >> 4;
  const int ob = wave * 48;

  bf16x4 afr[3][8];
  #pragma unroll
  for (int mt = 0; mt < 3; ++mt)
    #pragma unroll
    for (int ks = 0; ks < 8; ++ks)
      afr[mt][ks] = *(const bf16x4*)&wqb[(ob + mt*16 + tl)*C_ + ks*16 + g*4];

  const f32x4 zero = {0.f,0.f,0.f,0.f};
  f32x4 acc[3][5];
  #pragma unroll
  for (int mt = 0; mt < 3; ++mt)
    #pragma unroll
    for (int nt = 0; nt < 5; ++nt) acc[mt][nt] = zero;

  #pragma unroll
  for (int ks = 0; ks < 8; ++ks) {
    bf16x4 bfr[5];
    #pragma unroll
    for (int nt = 0; nt < 5; ++nt)
      bfr[nt] = *(const bf16x4*)&xs[nt*16 + tl][ks*16 + g*4];
    #pragma unroll
    for (int mt = 0; mt < 3; ++mt)
      #pragma unroll
      for (int nt = 0; nt < 5; ++nt)
        acc[mt][nt] = mfma16(afr[mt][ks], bfr[nt], acc[mt][nt]);
  }

  float bia[3][4], scm[3];
  #pragma unroll
  for (int mt = 0; mt < 3; ++mt) {
    scm[mt] = (ob + mt*16 < DK_) ? (0.5f*1.44269504f) : 1.f;
    #pragma unroll
    for (int r = 0; r < 4; ++r) bia[mt][r] = qkv_b[ob + mt*16 + g*4 + r];
  }

  #pragma unroll
  for (int nt = 0; nt < 5; ++nt) {
    int tg = t0 + nt*16 + tl;
    if (tg >= T_) continue;
    #pragma unroll
    for (int mt = 0; mt < 3; ++mt) {
      int o = ob + mt*16 + g*4;
      short* dst = &qkvb[((size_t)b*QO_ + o)*T_ + tg];
      #pragma unroll
      for (int r = 0; r < 4; ++r)
        dst[r*T_] = f2bf((acc[mt][nt][r] + bia[mt][r]) * scm[mt]);
    }
  }
}

// ---------------------------------------------------------------------------
// k_attn: R5-proven math (4 waves, rel K=16 block-diagonal, no-max softmax,
// pktr packing) with LEAN staging:
//   - K/Q compact [160][4] LDS (no d4..15 pads; g>0 lanes get zero frags)
//   - Q pre-scaled in k_qkv -> staging is pure copy
//   - kr table pre-converted to bf16 in k_prep -> uint copy
//   - all fills coalesced uint loads
// ---------------------------------------------------------------------------
__global__ __launch_bounds__(256) void k_attn(
    const short* __restrict__ qkvb, const short* __restrict__ krbg,
    short* __restrict__ o2b)
{
  const int bh = blockIdx.x;          // 0..3199
  const int b  = bh >> 3, h = bh & 7;
  __shared__ short kbc[160*4];        // K[s][d<4]                (1280 B)
  __shared__ short qbc[160*4];        // Q[t][d<4] pre-scaled     (1280 B)
  __shared__ short ve[16][164];       // V^T[e][s]                (5248 B)
  __shared__ short krb[336*4];        // kr rows bf16x4, row m+16 (2688 B)
  const short* base = qkvb + (size_t)b*QO_*T_;
  const int tid = threadIdx.x;

  for (int i = tid; i < 320; i += 256) {      // K: 2 s per uint
    int d = i / 80, j = i % 80, s = 2*j;
    unsigned u = 0;
    if (j < 75) u = *(const unsigned*)&base[(DK_ + h*4 + d)*T_ + s];
    kbc[s*4 + d] = (short)u;
    kbc[(s+1)*4 + d] = (short)(u >> 16);
  }
  for (int i = tid; i < 320; i += 256) {      // Q: 2 t per uint
    int d = i / 80, j = i % 80, t = 2*j;
    unsigned u = 0;
    if (j < 75) u = *(const unsigned*)&base[(h*4 + d)*T_ + t];
    qbc[t*4 + d] = (short)u;
    qbc[(t+1)*4 + d] = (short)(u >> 16);
  }
  for (int i = tid; i < 1280; i += 256) {     // V^T: uint copy
    int e = i / 80, j = i % 80;
    unsigned u = 0;
    if (j < 75) u = *(const unsigned*)&base[(2*DK_ + h*16 + e)*T_ + 2*j];
    *(unsigned*)&ve[e][2*j] = u;
  }
  for (int i = tid; i < 672; i += 256)        // kr: uint copy of bf16 table
    *(unsigned*)&krb[2*i] = *(const unsigned*)&krbg[2*i];
  __syncthreads();

  const int wave = tid >> 6, lane = tid & 63;
  const int tl = lane & 15, g = lane >> 4, soff = g << 2;

  const bf16x4 zerob = {0, 0, 0, 0};
  const f32x4 zero = {0.f, 0.f, 0.f, 0.f};

  bf16x4 kfr[10], vfr[10];
  #pragma unroll
  for (int st = 0; st < 10; ++st) {
    kfr[st] = (g == 0) ? *(const bf16x4*)&kbc[(st*16 + tl)*4] : zerob;
    vfr[st] = *(const bf16x4*)&ve[tl][st*16 + soff];
  }

  const bool act = (g == (tl & 3));   // lane holds B' nonzeros only here
  const int kca = tl >> 2;            // ...and only in this K-chunk

  for (int tt = wave; tt < 10; tt += 4) {
    const int t0 = tt*16, tg = t0 + tl;
    union { unsigned u[2]; bf16x4 v; } bqu;
    bqu.v = *(const bf16x4*)&qbc[tg*4];       // q row (pre-scaled)
    const bf16x4 qfr = (g == 0) ? bqu.v : zerob;

    f32x4 c[10];
    #pragma unroll
    for (int st = 0; st < 10; ++st) c[st] = mfma16(kfr[st], qfr, zero);

    bf16x4 brel[4];
    #pragma unroll
    for (int kc = 0; kc < 4; ++kc)
      brel[kc] = (act && kc == kca) ? bqu.v : zerob;

    // A' gather base: row = (tl - g + 165 - t0) + st*16 - kc*4
    const bf16x4* krp = ((const bf16x4*)krb) + (tl - g + 165 - t0);
    #pragma unroll
    for (int st = 0; st < 10; ++st)
      #pragma unroll
      for (int kc = 0; kc < 4; ++kc)
        c[st] = mfma16(krp[st*16 - kc*4], brel[kc], c[st]);

    // mask padded s rows (s = 144 + soff + i >= 150): exp2(-3e38) -> 0
    #pragma unroll
    for (int i = 0; i < 4; ++i)
      if (soff + i >= 6) c[9][i] = -3.0e38f;

    float l = 0.f;
    f32x4 acc = zero;
    #pragma unroll
    for (int st = 0; st < 10; ++st) {
      float p0 = __builtin_exp2f(c[st][0]);
      float p1 = __builtin_exp2f(c[st][1]);
      float p2 = __builtin_exp2f(c[st][2]);
      float p3 = __builtin_exp2f(c[st][3]);
      l += (p0 + p1) + (p2 + p3);
      union { unsigned u[2]; bf16x4 v; } pf;
      pf.u[0] = pktr(p0, p1); pf.u[1] = pktr(p2, p3);
      acc = mfma16(vfr[st], pf.v, acc);
    }
    l += __shfl_xor(l, 16);
    l += __shfl_xor(l, 32);
    const float inv = __builtin_amdgcn_rcpf(l);

    if (tg < T_) {
      unsigned u0 = pk2(acc[0]*inv, acc[1]*inv);
      unsigned u1 = pk2(acc[2]*inv, acc[3]*inv);
      *(uint2*)&o2b[((size_t)b*T_ + tg)*DV_ + h*16 + soff] = make_uint2(u0, u1);
    }
  }
}

// ---------------------------------------------------------------------------
// k_proj: bf16 MFMA GEMM  projb[b][o][t] = bf16(sum_c wab[o][c]*o2b[b][t][c] + attn_b[o])
// ---------------------------------------------------------------------------
__global__ __launch_bounds__(256) void k_proj(
    const short* __restrict__ o2b, const short* __restrict__ wab,
    const float* __restrict__ attn_b, short* __restrict__ projb)
{
  const int b = blockIdx.x, t0 = blockIdx.y * 80;
  __shared__ short xs[80][136];
  for (int i = threadIdx.x; i < 80*16; i += 256) {
    int tt = i >> 4, ch = i & 15, t = t0 + tt;
    short8 vv = {0,0,0,0,0,0,0,0};
    if (t < T_) vv = *(const short8*)&o2b[((size_t)b*T_ + t)*DV_ + ch*8];
    *(short8*)&xs[tt][ch*8] = vv;
  }
  __syncthreads();
  const int wave = threadIdx.x >> 6, lane = threadIdx.x & 63;
  const int tl = lane & 15, g = lane >> 4;
  const int ob = wave * 32;

  bf16x4 afr[2][8];
  #pragma unroll
  for (int mt = 0; mt < 2; ++mt)
    #pragma unroll
    for (int ks = 0; ks < 8; ++ks)
      afr[mt][ks] = *(const bf16x4*)&wab[(ob + mt*16 + tl)*DV_ + ks*16 + g*4];

  const f32x4 zero = {0.f,0.f,0.f,0.f};
  f32x4 acc[2][5];
  #pragma unroll
  for (int mt = 0; mt < 2; ++mt)
    #pragma unroll
    for (int nt = 0; nt < 5; ++nt) acc[mt][nt] = zero;

  #pragma unroll
  for (int ks = 0; ks < 8; ++ks) {
    bf16x4 bfr[5];
    #pragma unroll
    for (int nt = 0; nt < 5; ++nt)
      bfr[nt] = *(const bf16x4*)&xs[nt*16 + tl][ks*16 + g*4];
    #pragma unroll
    for (int mt = 0; mt < 2; ++mt)
      #pragma unroll
      for (int nt = 0; nt < 5; ++nt)
        acc[mt][nt] = mfma16(afr[mt][ks], bfr[nt], acc[mt][nt]);
  }

  float bia[2][4];
  #pragma unroll
  for (int mt = 0; mt < 2; ++mt)
    #pragma unroll
    for (int r = 0; r < 4; ++r) bia[mt][r] = attn_b[ob + mt*16 + g*4 + r];

  #pragma unroll
  for (int nt = 0; nt < 5; ++nt) {
    int tg = t0 + nt*16 + tl;
    if (tg >= T_) continue;
    #pragma unroll
    for (int mt = 0; mt < 2; ++mt) {
      int o = ob + mt*16 + g*4;
      short* dst = &projb[((size_t)b*DV_ + o)*T_ + tg];
      #pragma unroll
      for (int r = 0; r < 4; ++r)
        dst[r*T_] = f2bf(acc[mt][nt][r] + bia[mt][r]);
    }
  }
}

// ---------------------------------------------------------------------------
// k_final: transpose projb[b][o][t] -> out[n][o][t][v], + residual + BN + ReLU
// ---------------------------------------------------------------------------
__global__ __launch_bounds__(256) void k_final(
    const short* __restrict__ projb, const float* __restrict__ x,
    const float* __restrict__ bn_g, const float* __restrict__ bn_b,
    const float* __restrict__ bn_m, const float* __restrict__ bn_v,
    float* __restrict__ out)
{
  const int n = blockIdx.x, o = blockIdx.y;
  __shared__ short ls[V_*T_];
  for (int i = threadIdx.x; i < V_*T_; i += 256) {
    int v = i / T_, t = i % T_;
    ls[i] = projb[((size_t)(n*V_ + v)*DV_ + o)*T_ + t];
  }
  __syncthreads();
  const float sc = bn_g[o] * rsqrtf(bn_v[o] + EPS_);
  const float sh = bn_b[o] - bn_m[o]*sc;
  const size_t base = ((size_t)n*C_ + o)*(T_*V_);
  for (int j = threadIdx.x; j < T_*V_; j += 256) {
    int t = j / V_, v = j % V_;
    float pv = lo16((unsigned)(unsigned short)ls[v*T_ + t]);
    float r = (pv + x[base + j]) * sc + sh;
    out[base + j] = fmaxf(r, 0.f);
  }
}

// ---------------------------------------------------------------------------
extern "C" void kernel_launch(void* const* d_in, const int* in_sizes, int n_in,
                              void* d_out, int out_size, void* d_ws, size_t ws_size,
                              hipStream_t stream) {
  const float* x       = (const float*)d_in[0];
  const float* qkv_w   = (const float*)d_in[1];
  const float* qkv_b   = (const float*)d_in[2];
  const float* key_rel = (const float*)d_in[3];
  const float* attn_w  = (const float*)d_in[4];
  const float* attn_b  = (const float*)d_in[5];
  const float* dbn_g   = (const float*)d_in[6];
  const float* dbn_b   = (const float*)d_in[7];
  const float* dbn_m   = (const float*)d_in[8];
  const float* dbn_v   = (const float*)d_in[9];
  const float* bn_g    = (const float*)d_in[10];
  const float* bn_b    = (const float*)d_in[11];
  const float* bn_m    = (const float*)d_in[12];
  const float* bn_v    = (const float*)d_in[13];

  // ws layout: xtb/o2b | qkvb | proj region (bf16 uses half) | consts
  short* xtb  = (short*)d_ws;                          // 7.68M shorts, reused as o2b
  short* o2b  = xtb;
  short* qkvb = xtb + (size_t)B_*C_*T_;                // 11.52M shorts
  float* projf = (float*)(qkvb + (size_t)B_*QO_*T_);   // region reserved as before
  short* projb = (short*)projf;                        // bf16 actually used
  float* dsc  = projf + (size_t)B_*DV_*T_;             // 3200
  float* dsh  = dsc + C_*V_;                           // 3200
  short* wqb  = (short*)(dsh + C_*V_);                 // 24576 shorts
  short* wab  = wqb + QO_*C_;                          // 16384 shorts
  short* krbg = wab + DV_*DV_;                         // 1344 shorts (bf16 kr)
  float* outp = (float*)d_out;

  k_prep<<<32, 256, 0, stream>>>(qkv_w, attn_w, dbn_g, dbn_b, dbn_m, dbn_v,
                                 key_rel, wqb, wab, krbg, dsc, dsh);
  k_xt2<<<dim3(N_, 30), 256, 0, stream>>>(x, dsc, dsh, xtb);
  k_qkv<<<dim3(B_, 2), 256, 0, stream>>>(xtb, wqb, qkv_b, qkvb);
  k_attn<<<dim3(B_*NH_), 256, 0, stream>>>(qkvb, krbg, o2b);
  k_proj<<<dim3(B_, 2), 256, 0, stream>>>(o2b, wab, attn_b, projb);
  k_final<<<dim3(N_, DV_), 256, 0, stream>>>(projb, x, bn_g, bn_b, bn_m, bn_v, outp);
}